// Round 10
// baseline (341.335 us; speedup 1.0000x reference)
//
#include <hip/hip_runtime.h>
#include <math.h>

#define B_    32
#define C_    384
#define RHO_  25
#define WP_   256
#define PIX_  4096
#define D_    768
#define HID_  40
#define NROWS (B_*C_*RHO_)     // 307200
#define FE_N (RHO_*B_*D_)      // 614400
#define POLARBLK 2048

__device__ __forceinline__ float gelu_exact(float x) {
    return 0.5f * x * (1.f + erff(x * 0.70710678118654752f));
}

// ---------------- K1: bins via LDS atomics + W1 transpose + fe zero ----------------
__global__ __launch_bounds__(256) void prep_kernel(const float* __restrict__ grid,
        const float* __restrict__ W1_0, const float* __restrict__ W1s,
        float* __restrict__ bins, float* __restrict__ W1T, float* __restrict__ fe) {
    __shared__ float lb[PIX_];
    int tid = threadIdx.x;
    if (blockIdx.x < B_ * RHO_) {
        for (int i = tid; i < PIX_ / 4; i += 256) ((float4*)lb)[i] = make_float4(0.f, 0.f, 0.f, 0.f);
        __syncthreads();
        int pt = blockIdx.x * WP_ + tid;                 // (b,rho) block owns its 256 points
        float2 g = ((const float2*)grid)[pt];
        float ix = (g.x + 1.f) * 32.f - 0.5f;
        float iy = (g.y + 1.f) * 32.f - 0.5f;
        float x0f = floorf(ix), y0f = floorf(iy);
        float fx = ix - x0f, fy = iy - y0f;
        int x0 = (int)x0f, y0 = (int)y0f;
        const float s = 1.f / 256.f;
        if ((unsigned)x0 < 64u) {
            if ((unsigned)y0 < 64u)       atomicAdd(&lb[y0 * 64 + x0],       (1.f - fx) * (1.f - fy) * s);
            if ((unsigned)(y0 + 1) < 64u) atomicAdd(&lb[(y0 + 1) * 64 + x0], (1.f - fx) * fy * s);
        }
        if ((unsigned)(x0 + 1) < 64u) {
            if ((unsigned)y0 < 64u)       atomicAdd(&lb[y0 * 64 + x0 + 1],       fx * (1.f - fy) * s);
            if ((unsigned)(y0 + 1) < 64u) atomicAdd(&lb[(y0 + 1) * 64 + x0 + 1], fx * fy * s);
        }
        __syncthreads();
        float4* dst = (float4*)(bins + (size_t)blockIdx.x * PIX_);
        for (int i = tid; i < PIX_ / 4; i += 256) dst[i] = ((float4*)lb)[i];
    } else if (blockIdx.x < B_ * RHO_ + 25) {
        int i = blockIdx.x - B_ * RHO_;                  // head 0..24
        const float* src = (i == 0) ? W1_0 : (W1s + (size_t)(i - 1) * 769 * HID_);
        float* dst = W1T + (size_t)i * HID_ * D_;
        for (int idx = tid; idx < HID_ * D_; idx += 256) {
            int j = idx / D_, c = idx % D_;
            dst[idx] = src[c * HID_ + j];
        }
    } else {
        int z = blockIdx.x - (B_ * RHO_ + 25);           // 0..49, zero fe (cart half accumulated)
        float4* f4 = (float4*)fe;
        int per = FE_N / 4 / 50;                         // 3072 float4 per block
        for (int i = tid; i < per; i += 256)
            f4[z * per + i] = make_float4(0.f, 0.f, 0.f, 0.f);
    }
}

// ---------------- K2: polar mean over width; wave per row, ILP-4, full occupancy ----------------
__global__ __launch_bounds__(256) void polar_mean_kernel(const float* __restrict__ polar,
                                                         float* __restrict__ fe) {
    int wid = blockIdx.x * 4 + (threadIdx.x >> 6);
    int lane = threadIdx.x & 63;
    const int NW = POLARBLK * 4;                         // 8192 waves
    for (int r0 = wid; r0 < NROWS; r0 += 4 * NW) {
        float s[4];
        #pragma unroll
        for (int k = 0; k < 4; ++k) {
            int r = r0 + k * NW;
            float4 v = (r < NROWS) ? ((const float4*)(polar + (size_t)r * WP_))[lane]
                                   : make_float4(0.f, 0.f, 0.f, 0.f);
            s[k] = v.x + v.y + v.z + v.w;
        }
        #pragma unroll
        for (int m = 32; m >= 1; m >>= 1) {
            #pragma unroll
            for (int k = 0; k < 4; ++k) s[k] += __shfl_xor(s[k], m, 64);
        }
        if (lane == 0) {
            #pragma unroll
            for (int k = 0; k < 4; ++k) {
                int r = r0 + k * NW;
                if (r < NROWS) {
                    int rho = r % RHO_, cch = (r / RHO_) % C_, bb = r / (RHO_ * C_);
                    fe[((size_t)(rho * B_ + bb)) * D_ + cch] = s[k] * (1.f / 256.f);
                }
            }
        }
    }
}

// ---------------- K3: cart GEMM, wave-autonomous (no LDS, no barriers) ----------------
// Wave gw owns (b, pc p-chunk of 1024, 8-channel group). Lane = (j=lane>>3 channel,
// q=lane&7 p-quad). 32 tiles of 32 p: X via float4 register double-buffer, W (bins,
// L2/L3-resident) via broadcast float4 loads. acc[25]/lane; q-reduce via 3 shfls;
// atomicAdd into fe (4-way contention across pc).
__global__ __launch_bounds__(256) void cart_wave_kernel(const float* __restrict__ cart,
        const float* __restrict__ bins, float* __restrict__ fe) {
    int gw = blockIdx.x * 4 + (threadIdx.x >> 6);        // 0..6143
    int lane = threadIdx.x & 63;
    int cg = gw % 48;                                    // 8-channel group
    int pc = (gw / 48) % 4;                              // p-chunk
    int b  = gw / 192;
    int c0 = cg * 8;
    int j = lane >> 3, q = lane & 7;
    const float* xrow = cart + ((size_t)b * C_ + c0 + j) * PIX_ + pc * 1024 + q * 4;
    const float* wrow = bins + (size_t)b * RHO_ * PIX_ + pc * 1024 + q * 4;

    float acc[25];
    #pragma unroll
    for (int r = 0; r < 25; ++r) acc[r] = 0.f;

    float4 x0 = *(const float4*)(xrow);
    float4 x1 = *(const float4*)(xrow + 32);
    for (int t = 0; t < 32; ++t) {
        float4 xc = x0;
        x0 = x1;
        if (t < 30) x1 = *(const float4*)(xrow + (t + 2) * 32);
        const float* wt = wrow + t * 32;
        #pragma unroll
        for (int r = 0; r < 25; ++r) {
            float4 wv = *(const float4*)(wt + (size_t)r * PIX_);   // 8-way lane broadcast
            acc[r] += xc.x * wv.x + xc.y * wv.y + xc.z * wv.z + xc.w * wv.w;
        }
    }
    // reduce over q within each 8-lane group
    #pragma unroll
    for (int r = 0; r < 25; ++r) {
        acc[r] += __shfl_xor(acc[r], 1, 64);
        acc[r] += __shfl_xor(acc[r], 2, 64);
        acc[r] += __shfl_xor(acc[r], 4, 64);
    }
    if (q == 0) {
        int c = c0 + j;
        #pragma unroll
        for (int r = 0; r < 25; ++r)
            atomicAdd(&fe[((size_t)(r * B_ + b)) * D_ + 384 + c], acc[r]);
    }
}

// ---------------- K4: G[i][b][j] = fe[i][b][:] @ W1 + b1 ; wave per (i,b,j-half) ----------------
__global__ __launch_bounds__(256) void mlp_pre_kernel(const float* __restrict__ fe,
        const float* __restrict__ W1T, const float* __restrict__ b1_0,
        const float* __restrict__ b1s, float* __restrict__ G) {
    int lane = threadIdx.x & 63;
    int trip = blockIdx.x * 4 + (threadIdx.x >> 6);      // 0..1599 = (i,b,jh)
    int jh = trip & 1;
    int pair = trip >> 1;
    int i = pair >> 5, b = pair & 31;
    const float4* f4p = (const float4*)(fe + (size_t)(i * B_ + b) * D_);
    float4 f0 = f4p[lane], f1 = f4p[lane + 64], f2 = f4p[lane + 128];
    int j0 = jh * 20;
    #pragma unroll 2
    for (int j = j0; j < j0 + 20; ++j) {
        const float4* w4p = (const float4*)(W1T + ((size_t)i * HID_ + j) * D_);
        float4 w0 = w4p[lane], w1 = w4p[lane + 64], w2 = w4p[lane + 128];
        float s = f0.x*w0.x + f0.y*w0.y + f0.z*w0.z + f0.w*w0.w
                + f1.x*w1.x + f1.y*w1.y + f1.z*w1.z + f1.w*w1.w
                + f2.x*w2.x + f2.y*w2.y + f2.z*w2.z + f2.w*w2.w;
        #pragma unroll
        for (int m = 32; m >= 1; m >>= 1) s += __shfl_xor(s, m, 64);
        if (lane == 0) {
            float bias = (i == 0) ? b1_0[j] : b1s[(i - 1) * HID_ + j];
            G[(size_t)(i * B_ + b) * HID_ + j] = s + bias;
        }
    }
}

// ---------------- K5: sequential heads, register-resident, wave-synchronous ----------------
__global__ __launch_bounds__(64) void mlp_seq_kernel(const float* __restrict__ G,
        const float* __restrict__ W1s, const float* __restrict__ W2_0,
        const float* __restrict__ b2_0, const float* __restrict__ W2s,
        const float* __restrict__ b2s, float* __restrict__ out) {
    int lane = threadIdx.x;
    int j2 = lane & 31, b = blockIdx.x * 2 + (lane >> 5);
    bool hi = (j2 < 8);
    float g1[25], g2[25], wl1[25], wl2[25], w2a[25], w2b[25], bsc[25];
    #pragma unroll
    for (int i = 0; i < 25; ++i) {
        g1[i] = G[(size_t)(i * B_ + b) * HID_ + j2];
        g2[i] = hi ? G[(size_t)(i * B_ + b) * HID_ + 32 + j2] : 0.f;
    }
    wl1[0] = 0.f; wl2[0] = 0.f;
    w2a[0] = W2_0[j2]; w2b[0] = hi ? W2_0[32 + j2] : 0.f; bsc[0] = b2_0[0];
    #pragma unroll
    for (int i = 1; i < 25; ++i) {
        size_t base = ((size_t)(i - 1) * 769 + 768) * HID_;   // recurrent row of W1
        wl1[i] = W1s[base + j2];
        wl2[i] = hi ? W1s[base + 32 + j2] : 0.f;
        w2a[i] = W2s[(i - 1) * HID_ + j2];
        w2b[i] = hi ? W2s[(i - 1) * HID_ + 32 + j2] : 0.f;
        bsc[i] = b2s[i - 1];
    }
    float op = 0.f;
    #pragma unroll
    for (int i = 0; i < 25; ++i) {
        float x1 = g1[i] + op * wl1[i];
        float x2 = g2[i] + op * wl2[i];
        float p = gelu_exact(x1) * w2a[i] + gelu_exact(x2) * w2b[i];
        #pragma unroll
        for (int m = 16; m >= 1; m >>= 1) p += __shfl_xor(p, m, 64);   // stays within 32-lane group
        float o = p + bsc[i];
        op = o;
        if (j2 == 0) out[b * 25 + i] = fminf(fmaxf(o, 0.f), 3.14159265358979323846f);
    }
}

extern "C" void kernel_launch(void* const* d_in, const int* in_sizes, int n_in,
                              void* d_out, int out_size, void* d_ws, size_t ws_size,
                              hipStream_t stream) {
    const float* polar = (const float*)d_in[0];
    const float* cart  = (const float*)d_in[1];
    const float* grid  = (const float*)d_in[2];
    const float* W1_0  = (const float*)d_in[3];
    const float* b1_0  = (const float*)d_in[4];
    const float* W2_0  = (const float*)d_in[5];
    const float* b2_0  = (const float*)d_in[6];
    const float* W1s   = (const float*)d_in[7];
    const float* b1s   = (const float*)d_in[8];
    const float* W2s   = (const float*)d_in[9];
    const float* b2s   = (const float*)d_in[10];
    float* out = (float*)d_out;

    // ws layout (floats): bins[800*4096] | fe | G | W1T
    float* bins = (float*)d_ws;
    float* fe   = bins + (size_t)B_ * RHO_ * PIX_;
    float* G    = fe + (size_t)FE_N;
    float* W1T  = G + (size_t)RHO_ * B_ * HID_;

    prep_kernel<<<B_ * RHO_ + 25 + 50, 256, 0, stream>>>(grid, W1_0, W1s, bins, W1T, fe);
    polar_mean_kernel<<<POLARBLK, 256, 0, stream>>>(polar, fe);
    cart_wave_kernel<<<1536, 256, 0, stream>>>(cart, bins, fe);
    mlp_pre_kernel<<<(RHO_ * B_ * 2) / 4, 256, 0, stream>>>(fe, W1T, b1_0, b1s, G);
    mlp_seq_kernel<<<B_ / 2, 64, 0, stream>>>(G, W1s, W2_0, b2_0, W2s, b2s, out);
}

// Round 11
// 206.521 us; speedup vs baseline: 1.6528x; 1.6528x over previous
//
#include <hip/hip_runtime.h>
#include <math.h>

#define B_    32
#define C_    384
#define RHO_  25
#define WP_   256
#define PIX_  4096
#define D_    768
#define HID_  40
#define NROWS (B_*C_*RHO_)     // 307200
#define FE_N (RHO_*B_*D_)      // 614400
#define POLARBLK 2048

__device__ __forceinline__ float gelu_exact(float x) {
    return 0.5f * x * (1.f + erff(x * 0.70710678118654752f));
}

// ---------------- K1: bins via LDS atomics + W1 transpose + fe zero ----------------
__global__ __launch_bounds__(256) void prep_kernel(const float* __restrict__ grid,
        const float* __restrict__ W1_0, const float* __restrict__ W1s,
        float* __restrict__ bins, float* __restrict__ W1T, float* __restrict__ fe) {
    __shared__ float lb[PIX_];
    int tid = threadIdx.x;
    if (blockIdx.x < B_ * RHO_) {
        for (int i = tid; i < PIX_ / 4; i += 256) ((float4*)lb)[i] = make_float4(0.f, 0.f, 0.f, 0.f);
        __syncthreads();
        int pt = blockIdx.x * WP_ + tid;                 // (b,rho) block owns its 256 points
        float2 g = ((const float2*)grid)[pt];
        float ix = (g.x + 1.f) * 32.f - 0.5f;
        float iy = (g.y + 1.f) * 32.f - 0.5f;
        float x0f = floorf(ix), y0f = floorf(iy);
        float fx = ix - x0f, fy = iy - y0f;
        int x0 = (int)x0f, y0 = (int)y0f;
        const float s = 1.f / 256.f;
        if ((unsigned)x0 < 64u) {
            if ((unsigned)y0 < 64u)       atomicAdd(&lb[y0 * 64 + x0],       (1.f - fx) * (1.f - fy) * s);
            if ((unsigned)(y0 + 1) < 64u) atomicAdd(&lb[(y0 + 1) * 64 + x0], (1.f - fx) * fy * s);
        }
        if ((unsigned)(x0 + 1) < 64u) {
            if ((unsigned)y0 < 64u)       atomicAdd(&lb[y0 * 64 + x0 + 1],       fx * (1.f - fy) * s);
            if ((unsigned)(y0 + 1) < 64u) atomicAdd(&lb[(y0 + 1) * 64 + x0 + 1], fx * fy * s);
        }
        __syncthreads();
        float4* dst = (float4*)(bins + (size_t)blockIdx.x * PIX_);
        for (int i = tid; i < PIX_ / 4; i += 256) dst[i] = ((float4*)lb)[i];
    } else if (blockIdx.x < B_ * RHO_ + 25) {
        int i = blockIdx.x - B_ * RHO_;                  // head 0..24
        const float* src = (i == 0) ? W1_0 : (W1s + (size_t)(i - 1) * 769 * HID_);
        float* dst = W1T + (size_t)i * HID_ * D_;
        for (int idx = tid; idx < HID_ * D_; idx += 256) {
            int j = idx / D_, c = idx % D_;
            dst[idx] = src[c * HID_ + j];
        }
    } else {
        int z = blockIdx.x - (B_ * RHO_ + 25);           // 0..49, zero fe (cart half accumulated)
        float4* f4 = (float4*)fe;
        int per = FE_N / 4 / 50;                         // 3072 float4 per block
        for (int i = tid; i < per; i += 256)
            f4[z * per + i] = make_float4(0.f, 0.f, 0.f, 0.f);
    }
}

// ---------------- K2: polar mean over width; wave per row, ILP-4 ----------------
__global__ __launch_bounds__(256) void polar_mean_kernel(const float* __restrict__ polar,
                                                         float* __restrict__ fe) {
    int wid = blockIdx.x * 4 + (threadIdx.x >> 6);
    int lane = threadIdx.x & 63;
    const int NW = POLARBLK * 4;                         // 8192 waves
    for (int r0 = wid; r0 < NROWS; r0 += 4 * NW) {
        float s[4];
        #pragma unroll
        for (int k = 0; k < 4; ++k) {
            int r = r0 + k * NW;
            float4 v = (r < NROWS) ? ((const float4*)(polar + (size_t)r * WP_))[lane]
                                   : make_float4(0.f, 0.f, 0.f, 0.f);
            s[k] = v.x + v.y + v.z + v.w;
        }
        #pragma unroll
        for (int m = 32; m >= 1; m >>= 1) {
            #pragma unroll
            for (int k = 0; k < 4; ++k) s[k] += __shfl_xor(s[k], m, 64);
        }
        if (lane == 0) {
            #pragma unroll
            for (int k = 0; k < 4; ++k) {
                int r = r0 + k * NW;
                if (r < NROWS) {
                    int rho = r % RHO_, cch = (r / RHO_) % C_, bb = r / (RHO_ * C_);
                    fe[((size_t)(rho * B_ + bb)) * D_ + cch] = s[k] * (1.f / 256.f);
                }
            }
        }
    }
}

// ---------------- K3: cart GEMM, W LDS-resident, barrier-free compute loop ----------------
// Block = (b, 32-ch tile, 256-p chunk). Stage bins[b][0..24][chunk] (25.6 KB) once,
// then stream X with register dbuf. Lane = j(8 ch) x q(8 p-quads): X loads are 8x128B
// segments; LDS W reads span all 32 banks, 8-way same-address broadcast (conflict-free).
__global__ __launch_bounds__(256) void cart_lds_kernel(const float* __restrict__ cart,
        const float* __restrict__ bins, float* __restrict__ fe) {
    __shared__ float ldsW[6400];                         // 25 rho x 256 p
    int tid = threadIdx.x;
    int bid = blockIdx.x;                                // 0..6143
    int b   = bid / 192;
    int rem = bid % 192;
    int ct  = rem >> 4;
    int pc  = rem & 15;

    // stage W tile: 25 x 256 floats, coalesced
    {
        const float4* binb4 = (const float4*)(bins + (size_t)b * RHO_ * PIX_ + pc * 256);
        float4* lw4 = (float4*)ldsW;
        #pragma unroll 2
        for (int i = tid; i < 1600; i += 256) {
            int r = i >> 6, e = i & 63;
            lw4[(r << 6) + e] = binb4[(size_t)r * 1024 + e];
        }
    }
    __syncthreads();                                     // the only barrier

    int w = tid >> 6, lane = tid & 63;
    int j = lane >> 3, q = lane & 7;
    int c = ct * 32 + w * 8 + j;
    const float* xp = cart + ((size_t)b * C_ + c) * PIX_ + pc * 256 + q * 4;

    float acc[25];
    #pragma unroll
    for (int r = 0; r < 25; ++r) acc[r] = 0.f;

    float4 x0 = *(const float4*)(xp);
    float4 x1 = *(const float4*)(xp + 32);
    for (int t = 0; t < 8; ++t) {
        float4 xc = x0;
        x0 = x1;
        if (t < 6) x1 = *(const float4*)(xp + (t + 2) * 32);
        const float* wb = ldsW + t * 32 + q * 4;
        #pragma unroll
        for (int r = 0; r < 25; ++r) {
            float4 wv = *(const float4*)(wb + (r << 8));   // r*256; broadcast, conflict-free
            acc[r] += xc.x * wv.x + xc.y * wv.y + xc.z * wv.z + xc.w * wv.w;
        }
    }
    // fold q (lane bits 0..2)
    #pragma unroll
    for (int r = 0; r < 25; ++r) {
        acc[r] += __shfl_xor(acc[r], 1, 64);
        acc[r] += __shfl_xor(acc[r], 2, 64);
        acc[r] += __shfl_xor(acc[r], 4, 64);
    }
    if (q == 0) {
        #pragma unroll
        for (int r = 0; r < 25; ++r)
            atomicAdd(&fe[((size_t)(r * B_ + b)) * D_ + 384 + c], acc[r]);
    }
}

// ---------------- K4: G[i][b][j] = fe[i][b][:] @ W1 + b1 ; wave per (i,b,j-half) ----------------
__global__ __launch_bounds__(256) void mlp_pre_kernel(const float* __restrict__ fe,
        const float* __restrict__ W1T, const float* __restrict__ b1_0,
        const float* __restrict__ b1s, float* __restrict__ G) {
    int lane = threadIdx.x & 63;
    int trip = blockIdx.x * 4 + (threadIdx.x >> 6);      // 0..1599 = (i,b,jh)
    int jh = trip & 1;
    int pair = trip >> 1;
    int i = pair >> 5, b = pair & 31;
    const float4* f4p = (const float4*)(fe + (size_t)(i * B_ + b) * D_);
    float4 f0 = f4p[lane], f1 = f4p[lane + 64], f2 = f4p[lane + 128];
    int j0 = jh * 20;
    #pragma unroll 2
    for (int j = j0; j < j0 + 20; ++j) {
        const float4* w4p = (const float4*)(W1T + ((size_t)i * HID_ + j) * D_);
        float4 w0 = w4p[lane], w1 = w4p[lane + 64], w2 = w4p[lane + 128];
        float s = f0.x*w0.x + f0.y*w0.y + f0.z*w0.z + f0.w*w0.w
                + f1.x*w1.x + f1.y*w1.y + f1.z*w1.z + f1.w*w1.w
                + f2.x*w2.x + f2.y*w2.y + f2.z*w2.z + f2.w*w2.w;
        #pragma unroll
        for (int m = 32; m >= 1; m >>= 1) s += __shfl_xor(s, m, 64);
        if (lane == 0) {
            float bias = (i == 0) ? b1_0[j] : b1s[(i - 1) * HID_ + j];
            G[(size_t)(i * B_ + b) * HID_ + j] = s + bias;
        }
    }
}

// ---------------- K5: sequential heads, register-resident, wave-synchronous ----------------
__global__ __launch_bounds__(64) void mlp_seq_kernel(const float* __restrict__ G,
        const float* __restrict__ W1s, const float* __restrict__ W2_0,
        const float* __restrict__ b2_0, const float* __restrict__ W2s,
        const float* __restrict__ b2s, float* __restrict__ out) {
    int lane = threadIdx.x;
    int j2 = lane & 31, b = blockIdx.x * 2 + (lane >> 5);
    bool hi = (j2 < 8);
    float g1[25], g2[25], wl1[25], wl2[25], w2a[25], w2b[25], bsc[25];
    #pragma unroll
    for (int i = 0; i < 25; ++i) {
        g1[i] = G[(size_t)(i * B_ + b) * HID_ + j2];
        g2[i] = hi ? G[(size_t)(i * B_ + b) * HID_ + 32 + j2] : 0.f;
    }
    wl1[0] = 0.f; wl2[0] = 0.f;
    w2a[0] = W2_0[j2]; w2b[0] = hi ? W2_0[32 + j2] : 0.f; bsc[0] = b2_0[0];
    #pragma unroll
    for (int i = 1; i < 25; ++i) {
        size_t base = ((size_t)(i - 1) * 769 + 768) * HID_;   // recurrent row of W1
        wl1[i] = W1s[base + j2];
        wl2[i] = hi ? W1s[base + 32 + j2] : 0.f;
        w2a[i] = W2s[(i - 1) * HID_ + j2];
        w2b[i] = hi ? W2s[(i - 1) * HID_ + 32 + j2] : 0.f;
        bsc[i] = b2s[i - 1];
    }
    float op = 0.f;
    #pragma unroll
    for (int i = 0; i < 25; ++i) {
        float x1 = g1[i] + op * wl1[i];
        float x2 = g2[i] + op * wl2[i];
        float p = gelu_exact(x1) * w2a[i] + gelu_exact(x2) * w2b[i];
        #pragma unroll
        for (int m = 16; m >= 1; m >>= 1) p += __shfl_xor(p, m, 64);   // stays within 32-lane group
        float o = p + bsc[i];
        op = o;
        if (j2 == 0) out[b * 25 + i] = fminf(fmaxf(o, 0.f), 3.14159265358979323846f);
    }
}

extern "C" void kernel_launch(void* const* d_in, const int* in_sizes, int n_in,
                              void* d_out, int out_size, void* d_ws, size_t ws_size,
                              hipStream_t stream) {
    const float* polar = (const float*)d_in[0];
    const float* cart  = (const float*)d_in[1];
    const float* grid  = (const float*)d_in[2];
    const float* W1_0  = (const float*)d_in[3];
    const float* b1_0  = (const float*)d_in[4];
    const float* W2_0  = (const float*)d_in[5];
    const float* b2_0  = (const float*)d_in[6];
    const float* W1s   = (const float*)d_in[7];
    const float* b1s   = (const float*)d_in[8];
    const float* W2s   = (const float*)d_in[9];
    const float* b2s   = (const float*)d_in[10];
    float* out = (float*)d_out;

    // ws layout (floats): bins[800*4096] | fe | G | W1T
    float* bins = (float*)d_ws;
    float* fe   = bins + (size_t)B_ * RHO_ * PIX_;
    float* G    = fe + (size_t)FE_N;
    float* W1T  = G + (size_t)RHO_ * B_ * HID_;

    prep_kernel<<<B_ * RHO_ + 25 + 50, 256, 0, stream>>>(grid, W1_0, W1s, bins, W1T, fe);
    polar_mean_kernel<<<POLARBLK, 256, 0, stream>>>(polar, fe);
    cart_lds_kernel<<<B_ * 12 * 16, 256, 0, stream>>>(cart, bins, fe);
    mlp_pre_kernel<<<(RHO_ * B_ * 2) / 4, 256, 0, stream>>>(fe, W1T, b1_0, b1s, G);
    mlp_seq_kernel<<<B_ / 2, 64, 0, stream>>>(G, W1s, W2_0, b2_0, W2s, b2s, out);
}